// Round 1
// baseline (1312.895 us; speedup 1.0000x reference)
//
#include <hip/hip_runtime.h>
#include <stddef.h>

// Problem constants (match reference setup_inputs)
constexpr int N_NODES = 200000;
constexpr int N_EDGES = 200000;
constexpr int N_GRAPHS = 128;
constexpr int IN_F = 256;
constexpr int HID_F = 128;
constexpr int OUT_F = 128;
constexpr int OUT_W = OUT_F + HID_F; // 256 output cols per graph

// fused preprocessing kernel geometry: must be fully co-resident for the
// software grid barrier. 1024 blocks x 256 thr = 4 blocks/CU on 256 CUs;
// __launch_bounds__(256,4) caps VGPR<=128 so 4 blocks/CU always fit
// (wave limit 32/CU >> 16 needed, LDS 1KB).
constexpr int PRE_NB = 1024;
constexpr int PRE_T = PRE_NB * 256; // 262144 threads
static_assert(N_NODES <= PRE_T, "single-shot node phases");
static_assert(N_EDGES <= PRE_T, "single-shot edge phases");
static_assert(N_EDGES <= PRE_T - N_GRAPHS * OUT_F, "rootlin threads disjoint from edge threads");

typedef __attribute__((ext_vector_type(8))) short short8;   // bf16x8 MFMA A/B frag
typedef __attribute__((ext_vector_type(4))) float float4v;  // fp32x4 MFMA C/D frag

__device__ __forceinline__ short f2bf(float f) {
    union { float f; unsigned u; } v; v.f = f;
    unsigned r = v.u + 0x7fffu + ((v.u >> 16) & 1u);  // RNE
    return (short)(r >> 16);
}
__device__ __forceinline__ float bf2f(unsigned short s) {
    union { unsigned u; float f; } v; v.u = ((unsigned)s) << 16;
    return v.f;
}

// ---------------- software grid barrier (co-resident grid only) ----------------
// Fresh counter per sync point (bar[] pre-zeroed) -> no sense reversal needed.
__device__ __forceinline__ void grid_bar(int* bar, int idx, int nb) {
    __syncthreads();
    if (threadIdx.x == 0) {
        __threadfence(); // publish this block's prior global writes (device scope)
        __hip_atomic_fetch_add(&bar[idx], 1, __ATOMIC_RELEASE, __HIP_MEMORY_SCOPE_AGENT);
        while (__hip_atomic_load(&bar[idx], __ATOMIC_ACQUIRE, __HIP_MEMORY_SCOPE_AGENT) < nb)
            __builtin_amdgcn_s_sleep(2);
        __threadfence(); // order subsequent reads after observed release
    }
    __syncthreads();
}

// ---------------- fused preprocessing ----------------
// One kernel replaces: memset(cursor), edge_prep, scan_reduce, scan_base,
// scan_final, bucket, bounds, transpose_w, rootlin, memset(out).
// Phases (device-wide barrier between each):
//  P0: zero cnt, zero out, weight transposes, per-graph bounds (binary search)
//  P1: in-degree atomics over edges  ||  rootlin on the spare high threads
//  P2: block-local inclusive scan of counts (partial[b] = block sum)
//  P3: block 0 scans the 1024 partials in place -> exclusive bases
//  P4: rowptr/cursor/dinv finalize (dinv fused: rsqrt(1+indeg))
//  P5: bucket edges into CSR-by-dst via cursor atomics
__global__ __launch_bounds__(256, 4) void pre_fused_kernel(
    const int* __restrict__ src, const int* __restrict__ dst,
    const int* __restrict__ batch, const int* __restrict__ root_index,
    const float* __restrict__ x, const float* __restrict__ W1,
    const float* __restrict__ W2,
    int* __restrict__ cntcur,   // N_NODES: counts, then CSR cursor
    int* __restrict__ rp,       // N_NODES+1
    int* __restrict__ adj,      // N_EDGES
    int* __restrict__ partial,  // PRE_NB
    float* __restrict__ dinv,
    int* __restrict__ startv, int* __restrict__ cntg,
    short* __restrict__ Bt1, short* __restrict__ Bt2,
    float* __restrict__ rootlin, float* __restrict__ out,
    int* __restrict__ bar)
{
    __shared__ int sm[256];
    const int t = threadIdx.x;
    const int gid = blockIdx.x * 256 + t;

    // ---- P0 ----
    if (gid < N_NODES) cntcur[gid] = 0;
    if (gid < 128 * IN_F) { // Bt1[n*256+k] = bf16(W1[k*128+n])
        int n = gid >> 8, k = gid & 255;
        Bt1[n * IN_F + k] = f2bf(W1[(size_t)k * 128 + n]);
    }
    if (gid < 128 * HID_F) { // Bt2[n*128+k] = bf16(W2[k*128+n])
        int n = gid >> 7, k = gid & 127;
        Bt2[n * HID_F + k] = f2bf(W2[(size_t)k * 128 + n]);
    }
    if (gid < N_GRAPHS * OUT_W) out[gid] = 0.f;
    if (gid < N_GRAPHS) { // segment bounds on sorted batch
        int g = gid;
        int lo = 0, hi = N_NODES;
        while (lo < hi) { int mid = (lo + hi) >> 1; if (batch[mid] < g) lo = mid + 1; else hi = mid; }
        int lo2 = N_NODES;
        if (g != N_GRAPHS - 1) {
            int a = lo, b = N_NODES;
            while (a < b) { int mid = (a + b) >> 1; if (batch[mid] < g + 1) a = mid + 1; else b = mid; }
            lo2 = a;
        }
        startv[g] = lo;
        cntg[g] = lo2 - lo;
    }
    grid_bar(bar, 0, PRE_NB);

    // ---- P1: degree atomics || rootlin (disjoint thread ranges) ----
    if (gid < N_EDGES) {
        atomicAdd(&cntcur[dst[gid]], 1);
    } else if (gid >= PRE_T - N_GRAPHS * OUT_F) {
        // rootlin[g,f] = sum_k relu(x[root[g],k]) * W2[(HID_F+k)*OUT_F + f]
        int idx = gid - (PRE_T - N_GRAPHS * OUT_F);
        int g = idx >> 7, f = idx & 127;
        int r = root_index[g];
        const float* xr = x + (size_t)r * IN_F;
        float acc = 0.f;
        for (int k = 0; k < IN_F; ++k)
            acc += fmaxf(xr[k], 0.f) * W2[(size_t)(HID_F + k) * OUT_F + f];
        rootlin[(size_t)g * OUT_F + f] = acc;
    }
    grid_bar(bar, 1, PRE_NB);

    // ---- P2: block-local inclusive scan ----
    int v = (gid < N_NODES) ? cntcur[gid] : 0;
    sm[t] = v;
    __syncthreads();
    for (int ofs = 1; ofs < 256; ofs <<= 1) {
        int u = (t >= ofs) ? sm[t - ofs] : 0;
        __syncthreads();
        sm[t] += u;
        __syncthreads();
    }
    int lex = sm[t] - v; // local exclusive, kept in register across barriers
    if (t == 255) partial[blockIdx.x] = sm[255];
    grid_bar(bar, 2, PRE_NB);

    // ---- P3: block 0 scans PRE_NB partials in place -> exclusive bases ----
    if (blockIdx.x == 0) {
        int p0 = partial[t * 4 + 0], p1 = partial[t * 4 + 1];
        int p2 = partial[t * 4 + 2], p3 = partial[t * 4 + 3];
        int ts = p0 + p1 + p2 + p3;
        sm[t] = ts;
        __syncthreads();
        for (int ofs = 1; ofs < 256; ofs <<= 1) {
            int u = (t >= ofs) ? sm[t - ofs] : 0;
            __syncthreads();
            sm[t] += u;
            __syncthreads();
        }
        int ex = sm[t] - ts;
        partial[t * 4 + 0] = ex;
        partial[t * 4 + 1] = ex + p0;
        partial[t * 4 + 2] = ex + p0 + p1;
        partial[t * 4 + 3] = ex + p0 + p1 + p2;
    }
    grid_bar(bar, 3, PRE_NB);

    // ---- P4: finalize rowptr / cursor / dinv ----
    int base = partial[blockIdx.x];
    if (gid < N_NODES) {
        int ex = base + lex;
        rp[gid] = ex;
        cntcur[gid] = ex; // cursor for bucketing
        dinv[gid] = rsqrtf(1.0f + (float)v);
        if (gid == N_NODES - 1) rp[N_NODES] = ex + v;
    }
    grid_bar(bar, 4, PRE_NB);

    // ---- P5: bucket edges (CSR-by-dst; order within row arbitrary) ----
    if (gid < N_EDGES) {
        int pos = atomicAdd(&cntcur[dst[gid]], 1);
        adj[pos] = src[gid];
    }
}

// ---------------- bf16 MFMA GEMM (unchanged from tuned version) ----------------
// out[M,128] = op(A)[M,KTOT] @ B[KTOT,128], epilogue v = dinv[row]*(acc [+ rootlin]),
// stored as bf16. GATHER (conv2, KTOT==128): A-element for row d, col k is
//   relu(dinv[d]*(hs1[d,k] + sum_{in-edges} hs1[adj,k]) + bvec[k])  — pull-mode, no atomics.
template<int KTOT, bool GATHER, bool ADDROOT>
__global__ __launch_bounds__(256) void mfma_gemm_kernel(
    const void* __restrict__ Ap, const short* __restrict__ Bt,
    unsigned short* __restrict__ outp,
    const float* __restrict__ dinv, const float* __restrict__ bvec,
    const float* __restrict__ rootlin, const int* __restrict__ batch,
    const int* __restrict__ rp, const int* __restrict__ adj)
{
    // stride 136 shorts = 272B: bank stride 68 == 4 mod 32 -> 2-way conflicts only (free, m136)
    __shared__ __align__(16) short As[64][136];
    __shared__ __align__(16) short Bs[128][136];

    const int tid = threadIdx.x;
    const int wave = tid >> 6;
    const int lane = tid & 63;
    const int quad = lane >> 4;
    const int l16  = lane & 15;
    const int row0 = blockIdx.x * 64;

    float4v acc[8];
    #pragma unroll
    for (int c = 0; c < 8; ++c) acc[c] = (float4v){0.f, 0.f, 0.f, 0.f};

    const int arow = tid >> 2;
    const int ac8 = (tid & 3) * 8;
    const int bn = tid >> 1;
    const int bk = (tid & 1) * 64;

    for (int kb = 0; kb < KTOT / 128; ++kb) {
        {
            const short* bp = Bt + (size_t)bn * KTOT + kb * 128 + bk;
            #pragma unroll
            for (int j = 0; j < 8; ++j)
                *(short8*)&Bs[bn][bk + 8 * j] = *(const short8*)(bp + 8 * j);
        }
        if (GATHER) {
            const unsigned short* A = (const unsigned short*)Ap;
            const int row = row0 + arow;
            float sum[4][8];
            const unsigned short* hp = A + (size_t)row * 128 + ac8;
            #pragma unroll
            for (int jj = 0; jj < 4; ++jj) {
                short8 h = *(const short8*)(hp + 32 * jj);
                #pragma unroll
                for (int q = 0; q < 8; ++q) sum[jj][q] = bf2f((unsigned short)h[q]);
            }
            int e0 = rp[row], e1 = rp[row + 1];
            for (int e = e0; e < e1; ++e) {
                const unsigned short* qp = A + (size_t)adj[e] * 128 + ac8;
                #pragma unroll
                for (int jj = 0; jj < 4; ++jj) {
                    short8 h = *(const short8*)(qp + 32 * jj);
                    #pragma unroll
                    for (int q = 0; q < 8; ++q) sum[jj][q] += bf2f((unsigned short)h[q]);
                }
            }
            float asc = dinv[row];
            #pragma unroll
            for (int jj = 0; jj < 4; ++jj) {
                const float* bv = bvec + ac8 + 32 * jj;
                short8 s;
                #pragma unroll
                for (int q = 0; q < 8; ++q)
                    s[q] = f2bf(fmaxf(asc * sum[jj][q] + bv[q], 0.f));
                *(short8*)&As[arow][ac8 + 32 * jj] = s;
            }
        } else {
            const float* A = (const float*)Ap;
            const float* ap = A + (size_t)(row0 + arow) * KTOT + kb * 128 + ac8;
            #pragma unroll
            for (int jj = 0; jj < 4; ++jj) {
                float4 f0 = *(const float4*)(ap + 32 * jj);
                float4 f1 = *(const float4*)(ap + 32 * jj + 4);
                short8 s;
                s[0] = f2bf(f0.x); s[1] = f2bf(f0.y); s[2] = f2bf(f0.z); s[3] = f2bf(f0.w);
                s[4] = f2bf(f1.x); s[5] = f2bf(f1.y); s[6] = f2bf(f1.z); s[7] = f2bf(f1.w);
                *(short8*)&As[arow][ac8 + 32 * jj] = s;
            }
        }
        __syncthreads();
        #pragma unroll
        for (int ks = 0; ks < 4; ++ks) {
            short8 af = *(const short8*)&As[wave * 16 + l16][ks * 32 + quad * 8];
            #pragma unroll
            for (int c = 0; c < 8; ++c) {
                short8 bf = *(const short8*)&Bs[c * 16 + l16][ks * 32 + quad * 8];
                acc[c] = __builtin_amdgcn_mfma_f32_16x16x32_bf16(af, bf, acc[c], 0, 0, 0);
            }
        }
        __syncthreads();
    }

    #pragma unroll
    for (int r = 0; r < 4; ++r) {
        int row = row0 + wave * 16 + quad * 4 + r;
        float di = dinv[row];
        const float* rl = nullptr;
        if (ADDROOT) rl = rootlin + (size_t)batch[row] * 128;
        #pragma unroll
        for (int c = 0; c < 8; ++c) {
            int col = c * 16 + l16;
            float v = acc[c][r];
            if (ADDROOT) v += rl[col];
            outp[(size_t)row * 128 + col] = (unsigned short)f2bf(v * di);
        }
    }
}

// out[g,0:128]   = (1/n) sum_seg relu(dinv[i]*(hs2[i]+sum_in hs2[adj]) + b2)   (pull-mode conv2)
// out[g,128:256] = n>0 ? dinv[r]*(hs1[r]+sum_in hs1[adj]) + b1 : 0             (x2[root] on the fly)
__global__ void mean_kernel(const unsigned short* __restrict__ hs2,
                            const unsigned short* __restrict__ hs1,
                            const float* __restrict__ dinv, const float* __restrict__ b1v,
                            const float* __restrict__ b2v, const int* __restrict__ root_index,
                            const int* __restrict__ cnt, const int* __restrict__ start,
                            const int* __restrict__ rp, const int* __restrict__ adj,
                            float* __restrict__ out, int chunks)
{
    int g = blockIdx.x;
    int c = blockIdx.y;
    int f = threadIdx.x; // 128
    int s = start[g], n = cnt[g];
    int per = (n + chunks - 1) / chunks;
    int lo = s + c * per;
    int hi = min(s + n, lo + per);
    float bb = b2v[f];
    float accv = 0.f;
    for (int i = lo; i < hi; ++i) {
        float v = bf2f(hs2[(size_t)i * 128 + f]);
        int e0 = rp[i], e1 = rp[i + 1];
        for (int e = e0; e < e1; ++e)
            v += bf2f(hs2[(size_t)adj[e] * 128 + f]);
        accv += fmaxf(dinv[i] * v + bb, 0.f);
    }
    if (hi > lo)
        atomicAdd(&out[(size_t)g * OUT_W + f], accv / (float)max(n, 1));
    if (c == 0) {
        int r = root_index[g];
        float v = 0.f;
        if (n > 0) {
            v = bf2f(hs1[(size_t)r * 128 + f]);
            int e0 = rp[r], e1 = rp[r + 1];
            for (int e = e0; e < e1; ++e)
                v += bf2f(hs1[(size_t)adj[e] * 128 + f]);
            v = dinv[r] * v + b1v[f];
        }
        out[(size_t)g * OUT_W + HID_F + f] = v;
    }
}

// ---------------- launch ----------------

static inline size_t align_up(size_t x, size_t a) { return (x + a - 1) / a * a; }

extern "C" void kernel_launch(void* const* d_in, const int* in_sizes, int n_in,
                              void* d_out, int out_size, void* d_ws, size_t ws_size,
                              hipStream_t stream) {
    const float* x = (const float*)d_in[0];
    const int* ei = (const int*)d_in[1];
    const int* batch = (const int*)d_in[2];
    const int* root = (const int*)d_in[3];
    const float* W1 = (const float*)d_in[4];
    const float* b1 = (const float*)d_in[5];
    const float* W2 = (const float*)d_in[6];
    const float* b2 = (const float*)d_in[7];
    float* out = (float*)d_out;

    const int* src = ei;
    const int* dst = ei + N_EDGES;

    // workspace carve-up
    char* ws = (char*)d_ws;
    size_t off = 0;
    const size_t NB16 = (size_t)N_NODES * 128 * sizeof(unsigned short); // 51.2 MB

    float* dinv = (float*)(ws + off);    off = align_up(off + (size_t)N_NODES * sizeof(float), 256);
    int* cntg = (int*)(ws + off);        off = align_up(off + N_GRAPHS * sizeof(int), 256);
    int* startv = (int*)(ws + off);      off = align_up(off + N_GRAPHS * sizeof(int), 256);
    float* rootlin = (float*)(ws + off); off = align_up(off + (size_t)N_GRAPHS * OUT_F * sizeof(float), 256);
    short* Bt1 = (short*)(ws + off);     off = align_up(off + (size_t)128 * IN_F * sizeof(short), 256);
    short* Bt2 = (short*)(ws + off);     off = align_up(off + (size_t)128 * HID_F * sizeof(short), 256);
    int* rowptr = (int*)(ws + off);      off = align_up(off + (size_t)(N_NODES + 1) * sizeof(int), 256);
    int* cntcur = (int*)(ws + off);      off = align_up(off + (size_t)N_NODES * sizeof(int), 256);
    int* partial = (int*)(ws + off);     off = align_up(off + (size_t)PRE_NB * sizeof(int), 256);
    int* bar = (int*)(ws + off);         off = align_up(off + 8 * sizeof(int), 256);
    int* adj = (int*)(ws + off);         off = align_up(off + (size_t)N_EDGES * sizeof(int), 256);
    unsigned short* hs1 = (unsigned short*)(ws + off); off = align_up(off + NB16, 256);
    unsigned short* hs2 = (unsigned short*)(ws + off); off = align_up(off + NB16, 256);
    (void)ws_size; (void)n_in; (void)in_sizes; (void)out_size;

    // grid-barrier counters must start at zero (workspace is poisoned)
    hipMemsetAsync(bar, 0, 8 * sizeof(int), stream);

    // fused preamble: degrees -> scan -> CSR bucket, bounds, transposes,
    // rootlin, dinv, out-zero. One launch, 5 software grid barriers.
    pre_fused_kernel<<<PRE_NB, 256, 0, stream>>>(
        src, dst, batch, root, x, W1, W2,
        cntcur, rowptr, adj, partial, dinv, startv, cntg,
        Bt1, Bt2, rootlin, out, bar);

    // conv1 linear: hs1 = bf16( dinv .* (x @ W1) )
    mfma_gemm_kernel<IN_F, false, false><<<N_NODES / 64, 256, 0, stream>>>(
        x, Bt1, hs1, dinv, nullptr, nullptr, nullptr, nullptr, nullptr);

    // conv2 linear, pulling conv1 aggregation via CSR in the A-staging
    mfma_gemm_kernel<HID_F, true, true><<<N_NODES / 64, 256, 0, stream>>>(
        hs1, Bt2, hs2, dinv, b1, rootlin, batch, rowptr, adj);

    // fused conv2-aggregation + relu + graph mean + root gather
    dim3 mg(N_GRAPHS, 32);
    mean_kernel<<<mg, 128, 0, stream>>>(hs2, hs1, dinv, b1, b2, root, cntg, startv,
                                        rowptr, adj, out, 32);
}

// Round 2
// 553.742 us; speedup vs baseline: 2.3710x; 2.3710x over previous
//
#include <hip/hip_runtime.h>
#include <stddef.h>

// Problem constants (match reference setup_inputs)
constexpr int N_NODES = 200000;
constexpr int N_EDGES = 200000;
constexpr int N_GRAPHS = 128;
constexpr int IN_F = 256;
constexpr int HID_F = 128;
constexpr int OUT_F = 128;
constexpr int OUT_W = OUT_F + HID_F; // 256 output cols per graph

// fused preprocessing kernel geometry: must be fully co-resident for the
// software grid barrier. 1024 blocks x 256 thr = 4 blocks/CU on 256 CUs;
// __launch_bounds__(256,4) caps VGPR<=128 so 4 blocks/CU always fit
// (verified r1: OccupancyPercent ~49% = 16/32 waves -> co-resident).
constexpr int PRE_NB = 1024;
constexpr int PRE_T = PRE_NB * 256; // 262144 threads
static_assert(N_NODES <= PRE_T, "single-shot node phases");
static_assert(N_EDGES <= PRE_T, "single-shot edge phases");
static_assert(N_EDGES <= PRE_T - N_GRAPHS * OUT_F, "rootlin threads disjoint from edge threads");

typedef __attribute__((ext_vector_type(8))) short short8;   // bf16x8 MFMA A/B frag
typedef __attribute__((ext_vector_type(4))) float float4v;  // fp32x4 MFMA C/D frag

__device__ __forceinline__ short f2bf(float f) {
    union { float f; unsigned u; } v; v.f = f;
    unsigned r = v.u + 0x7fffu + ((v.u >> 16) & 1u);  // RNE
    return (short)(r >> 16);
}
__device__ __forceinline__ float bf2f(unsigned short s) {
    union { unsigned u; float f; } v; v.u = ((unsigned)s) << 16;
    return v.f;
}

// ---- coherent-point (cross-XCD) relaxed accessors: sc1 ops, no L2 flush ----
__device__ __forceinline__ void cstore(int* p, int v) {
    __hip_atomic_store(p, v, __ATOMIC_RELAXED, __HIP_MEMORY_SCOPE_AGENT);
}
__device__ __forceinline__ int cload(const int* p) {
    return __hip_atomic_load(p, __ATOMIC_RELAXED, __HIP_MEMORY_SCOPE_AGENT);
}

// ---------------- software grid barrier (co-resident grid only) ----------------
// r1 post-mortem: acquire-poll + __threadfence emitted buffer_inv/wbl2 per
// iteration/block -> continuous L2 invalidation starved the working blocks
// (978us, VALUBusy 0.1%). Fix: RELAXED add + RELAXED poll (sc1, no cache
// maintenance). Ordering: grid_bar's own __syncthreads() drains vmcnt(0)
// before s_barrier [HIP-compiler], so each block's prior sc1 writes are at
// the coherent point before its increment becomes visible.
__device__ __forceinline__ void grid_bar(int* bar, int idx, int nb) {
    __syncthreads();
    if (threadIdx.x == 0) {
        __hip_atomic_fetch_add(&bar[idx], 1, __ATOMIC_RELAXED, __HIP_MEMORY_SCOPE_AGENT);
        while (__hip_atomic_load(&bar[idx], __ATOMIC_RELAXED, __HIP_MEMORY_SCOPE_AGENT) < nb)
            __builtin_amdgcn_s_sleep(8);
    }
    __syncthreads();
}

// ---------------- fused preprocessing ----------------
// One kernel replaces: memset(cursor), edge_prep, scan_reduce, scan_base,
// scan_final, bucket, bounds, transpose_w, rootlin, memset(out).
// Cross-phase in-kernel data (cntcur, partial) uses sc1 relaxed atomics
// (coherent point, no stale per-XCD L2 lines). Data read only by LATER
// kernels (rp/adj/dinv/Bt/rootlin/out/bounds) uses plain cached stores —
// kernel-end release flushes them.
__global__ __launch_bounds__(256, 4) void pre_fused_kernel(
    const int* __restrict__ src, const int* __restrict__ dst,
    const int* __restrict__ batch, const int* __restrict__ root_index,
    const float* __restrict__ x, const float* __restrict__ W1,
    const float* __restrict__ W2,
    int* __restrict__ cntcur,   // N_NODES: counts, then CSR cursor
    int* __restrict__ rp,       // N_NODES+1
    int* __restrict__ adj,      // N_EDGES
    int* __restrict__ partial,  // PRE_NB
    float* __restrict__ dinv,
    int* __restrict__ startv, int* __restrict__ cntg,
    short* __restrict__ Bt1, short* __restrict__ Bt2,
    float* __restrict__ rootlin, float* __restrict__ out,
    int* __restrict__ bar)
{
    __shared__ int sm[256];
    const int t = threadIdx.x;
    const int gid = blockIdx.x * 256 + t;

    // ---- P0 ----
    if (gid < N_NODES) cstore(&cntcur[gid], 0);
    if (gid < 128 * IN_F) { // Bt1[n*256+k] = bf16(W1[k*128+n])
        int n = gid >> 8, k = gid & 255;
        Bt1[n * IN_F + k] = f2bf(W1[(size_t)k * 128 + n]);
    }
    if (gid < 128 * HID_F) { // Bt2[n*128+k] = bf16(W2[k*128+n])
        int n = gid >> 7, k = gid & 127;
        Bt2[n * HID_F + k] = f2bf(W2[(size_t)k * 128 + n]);
    }
    if (gid < N_GRAPHS * OUT_W) out[gid] = 0.f;
    if (gid < N_GRAPHS) { // segment bounds on sorted batch
        int g = gid;
        int lo = 0, hi = N_NODES;
        while (lo < hi) { int mid = (lo + hi) >> 1; if (batch[mid] < g) lo = mid + 1; else hi = mid; }
        int lo2 = N_NODES;
        if (g != N_GRAPHS - 1) {
            int a = lo, b = N_NODES;
            while (a < b) { int mid = (a + b) >> 1; if (batch[mid] < g + 1) a = mid + 1; else b = mid; }
            lo2 = a;
        }
        startv[g] = lo;
        cntg[g] = lo2 - lo;
    }
    grid_bar(bar, 0, PRE_NB);

    // ---- P1: degree atomics || rootlin (disjoint thread ranges) ----
    if (gid < N_EDGES) {
        atomicAdd(&cntcur[gid < N_EDGES ? dst[gid] : 0], 1);
    } else if (gid >= PRE_T - N_GRAPHS * OUT_F) {
        // rootlin[g,f] = sum_k relu(x[root[g],k]) * W2[(HID_F+k)*OUT_F + f]
        int idx = gid - (PRE_T - N_GRAPHS * OUT_F);
        int g = idx >> 7, f = idx & 127;
        int r = root_index[g];
        const float* xr = x + (size_t)r * IN_F;
        float acc = 0.f;
        for (int k = 0; k < IN_F; ++k)
            acc += fmaxf(xr[k], 0.f) * W2[(size_t)(HID_F + k) * OUT_F + f];
        rootlin[(size_t)g * OUT_F + f] = acc;
    }
    grid_bar(bar, 1, PRE_NB);

    // ---- P2: block-local inclusive scan of counts ----
    int v = (gid < N_NODES) ? cload(&cntcur[gid]) : 0;
    sm[t] = v;
    __syncthreads();
    for (int ofs = 1; ofs < 256; ofs <<= 1) {
        int u = (t >= ofs) ? sm[t - ofs] : 0;
        __syncthreads();
        sm[t] += u;
        __syncthreads();
    }
    int lex = sm[t] - v; // local exclusive, kept in register across barriers
    if (t == 255) cstore(&partial[blockIdx.x], sm[255]);
    grid_bar(bar, 2, PRE_NB);

    // ---- P3: block 0 scans PRE_NB partials in place -> exclusive bases ----
    if (blockIdx.x == 0) {
        int p0 = cload(&partial[t * 4 + 0]), p1 = cload(&partial[t * 4 + 1]);
        int p2 = cload(&partial[t * 4 + 2]), p3 = cload(&partial[t * 4 + 3]);
        int ts = p0 + p1 + p2 + p3;
        sm[t] = ts;
        __syncthreads();
        for (int ofs = 1; ofs < 256; ofs <<= 1) {
            int u = (t >= ofs) ? sm[t - ofs] : 0;
            __syncthreads();
            sm[t] += u;
            __syncthreads();
        }
        int ex = sm[t] - ts;
        cstore(&partial[t * 4 + 0], ex);
        cstore(&partial[t * 4 + 1], ex + p0);
        cstore(&partial[t * 4 + 2], ex + p0 + p1);
        cstore(&partial[t * 4 + 3], ex + p0 + p1 + p2);
    }
    grid_bar(bar, 3, PRE_NB);

    // ---- P4: finalize rowptr / cursor / dinv ----
    int base = cload(&partial[blockIdx.x]);
    if (gid < N_NODES) {
        int ex = base + lex;
        rp[gid] = ex;
        cstore(&cntcur[gid], ex); // cursor for bucketing (read by P5 atomics)
        dinv[gid] = rsqrtf(1.0f + (float)v);
        if (gid == N_NODES - 1) rp[N_NODES] = ex + v;
    }
    grid_bar(bar, 4, PRE_NB);

    // ---- P5: bucket edges (CSR-by-dst; order within row arbitrary) ----
    if (gid < N_EDGES) {
        int pos = atomicAdd(&cntcur[dst[gid]], 1);
        adj[pos] = src[gid];
    }
}

// ---------------- bf16 MFMA GEMM (unchanged from tuned version) ----------------
// out[M,128] = op(A)[M,KTOT] @ B[KTOT,128], epilogue v = dinv[row]*(acc [+ rootlin]),
// stored as bf16. GATHER (conv2, KTOT==128): A-element for row d, col k is
//   relu(dinv[d]*(hs1[d,k] + sum_{in-edges} hs1[adj,k]) + bvec[k])  — pull-mode, no atomics.
template<int KTOT, bool GATHER, bool ADDROOT>
__global__ __launch_bounds__(256) void mfma_gemm_kernel(
    const void* __restrict__ Ap, const short* __restrict__ Bt,
    unsigned short* __restrict__ outp,
    const float* __restrict__ dinv, const float* __restrict__ bvec,
    const float* __restrict__ rootlin, const int* __restrict__ batch,
    const int* __restrict__ rp, const int* __restrict__ adj)
{
    // stride 136 shorts = 272B: bank stride 68 == 4 mod 32 -> 2-way conflicts only (free, m136)
    __shared__ __align__(16) short As[64][136];
    __shared__ __align__(16) short Bs[128][136];

    const int tid = threadIdx.x;
    const int wave = tid >> 6;
    const int lane = tid & 63;
    const int quad = lane >> 4;
    const int l16  = lane & 15;
    const int row0 = blockIdx.x * 64;

    float4v acc[8];
    #pragma unroll
    for (int c = 0; c < 8; ++c) acc[c] = (float4v){0.f, 0.f, 0.f, 0.f};

    const int arow = tid >> 2;
    const int ac8 = (tid & 3) * 8;
    const int bn = tid >> 1;
    const int bk = (tid & 1) * 64;

    for (int kb = 0; kb < KTOT / 128; ++kb) {
        {
            const short* bp = Bt + (size_t)bn * KTOT + kb * 128 + bk;
            #pragma unroll
            for (int j = 0; j < 8; ++j)
                *(short8*)&Bs[bn][bk + 8 * j] = *(const short8*)(bp + 8 * j);
        }
        if (GATHER) {
            const unsigned short* A = (const unsigned short*)Ap;
            const int row = row0 + arow;
            float sum[4][8];
            const unsigned short* hp = A + (size_t)row * 128 + ac8;
            #pragma unroll
            for (int jj = 0; jj < 4; ++jj) {
                short8 h = *(const short8*)(hp + 32 * jj);
                #pragma unroll
                for (int q = 0; q < 8; ++q) sum[jj][q] = bf2f((unsigned short)h[q]);
            }
            int e0 = rp[row], e1 = rp[row + 1];
            for (int e = e0; e < e1; ++e) {
                const unsigned short* qp = A + (size_t)adj[e] * 128 + ac8;
                #pragma unroll
                for (int jj = 0; jj < 4; ++jj) {
                    short8 h = *(const short8*)(qp + 32 * jj);
                    #pragma unroll
                    for (int q = 0; q < 8; ++q) sum[jj][q] += bf2f((unsigned short)h[q]);
                }
            }
            float asc = dinv[row];
            #pragma unroll
            for (int jj = 0; jj < 4; ++jj) {
                const float* bv = bvec + ac8 + 32 * jj;
                short8 s;
                #pragma unroll
                for (int q = 0; q < 8; ++q)
                    s[q] = f2bf(fmaxf(asc * sum[jj][q] + bv[q], 0.f));
                *(short8*)&As[arow][ac8 + 32 * jj] = s;
            }
        } else {
            const float* A = (const float*)Ap;
            const float* ap = A + (size_t)(row0 + arow) * KTOT + kb * 128 + ac8;
            #pragma unroll
            for (int jj = 0; jj < 4; ++jj) {
                float4 f0 = *(const float4*)(ap + 32 * jj);
                float4 f1 = *(const float4*)(ap + 32 * jj + 4);
                short8 s;
                s[0] = f2bf(f0.x); s[1] = f2bf(f0.y); s[2] = f2bf(f0.z); s[3] = f2bf(f0.w);
                s[4] = f2bf(f1.x); s[5] = f2bf(f1.y); s[6] = f2bf(f1.z); s[7] = f2bf(f1.w);
                *(short8*)&As[arow][ac8 + 32 * jj] = s;
            }
        }
        __syncthreads();
        #pragma unroll
        for (int ks = 0; ks < 4; ++ks) {
            short8 af = *(const short8*)&As[wave * 16 + l16][ks * 32 + quad * 8];
            #pragma unroll
            for (int c = 0; c < 8; ++c) {
                short8 bf = *(const short8*)&Bs[c * 16 + l16][ks * 32 + quad * 8];
                acc[c] = __builtin_amdgcn_mfma_f32_16x16x32_bf16(af, bf, acc[c], 0, 0, 0);
            }
        }
        __syncthreads();
    }

    #pragma unroll
    for (int r = 0; r < 4; ++r) {
        int row = row0 + wave * 16 + quad * 4 + r;
        float di = dinv[row];
        const float* rl = nullptr;
        if (ADDROOT) rl = rootlin + (size_t)batch[row] * 128;
        #pragma unroll
        for (int c = 0; c < 8; ++c) {
            int col = c * 16 + l16;
            float v = acc[c][r];
            if (ADDROOT) v += rl[col];
            outp[(size_t)row * 128 + col] = (unsigned short)f2bf(v * di);
        }
    }
}

// out[g,0:128]   = (1/n) sum_seg relu(dinv[i]*(hs2[i]+sum_in hs2[adj]) + b2)   (pull-mode conv2)
// out[g,128:256] = n>0 ? dinv[r]*(hs1[r]+sum_in hs1[adj]) + b1 : 0             (x2[root] on the fly)
__global__ void mean_kernel(const unsigned short* __restrict__ hs2,
                            const unsigned short* __restrict__ hs1,
                            const float* __restrict__ dinv, const float* __restrict__ b1v,
                            const float* __restrict__ b2v, const int* __restrict__ root_index,
                            const int* __restrict__ cnt, const int* __restrict__ start,
                            const int* __restrict__ rp, const int* __restrict__ adj,
                            float* __restrict__ out, int chunks)
{
    int g = blockIdx.x;
    int c = blockIdx.y;
    int f = threadIdx.x; // 128
    int s = start[g], n = cnt[g];
    int per = (n + chunks - 1) / chunks;
    int lo = s + c * per;
    int hi = min(s + n, lo + per);
    float bb = b2v[f];
    float accv = 0.f;
    for (int i = lo; i < hi; ++i) {
        float v = bf2f(hs2[(size_t)i * 128 + f]);
        int e0 = rp[i], e1 = rp[i + 1];
        for (int e = e0; e < e1; ++e)
            v += bf2f(hs2[(size_t)adj[e] * 128 + f]);
        accv += fmaxf(dinv[i] * v + bb, 0.f);
    }
    if (hi > lo)
        atomicAdd(&out[(size_t)g * OUT_W + f], accv / (float)max(n, 1));
    if (c == 0) {
        int r = root_index[g];
        float v = 0.f;
        if (n > 0) {
            v = bf2f(hs1[(size_t)r * 128 + f]);
            int e0 = rp[r], e1 = rp[r + 1];
            for (int e = e0; e < e1; ++e)
                v += bf2f(hs1[(size_t)adj[e] * 128 + f]);
            v = dinv[r] * v + b1v[f];
        }
        out[(size_t)g * OUT_W + HID_F + f] = v;
    }
}

// ---------------- launch ----------------

static inline size_t align_up(size_t x, size_t a) { return (x + a - 1) / a * a; }

extern "C" void kernel_launch(void* const* d_in, const int* in_sizes, int n_in,
                              void* d_out, int out_size, void* d_ws, size_t ws_size,
                              hipStream_t stream) {
    const float* x = (const float*)d_in[0];
    const int* ei = (const int*)d_in[1];
    const int* batch = (const int*)d_in[2];
    const int* root = (const int*)d_in[3];
    const float* W1 = (const float*)d_in[4];
    const float* b1 = (const float*)d_in[5];
    const float* W2 = (const float*)d_in[6];
    const float* b2 = (const float*)d_in[7];
    float* out = (float*)d_out;

    const int* src = ei;
    const int* dst = ei + N_EDGES;

    // workspace carve-up
    char* ws = (char*)d_ws;
    size_t off = 0;
    const size_t NB16 = (size_t)N_NODES * 128 * sizeof(unsigned short); // 51.2 MB

    float* dinv = (float*)(ws + off);    off = align_up(off + (size_t)N_NODES * sizeof(float), 256);
    int* cntg = (int*)(ws + off);        off = align_up(off + N_GRAPHS * sizeof(int), 256);
    int* startv = (int*)(ws + off);      off = align_up(off + N_GRAPHS * sizeof(int), 256);
    float* rootlin = (float*)(ws + off); off = align_up(off + (size_t)N_GRAPHS * OUT_F * sizeof(float), 256);
    short* Bt1 = (short*)(ws + off);     off = align_up(off + (size_t)128 * IN_F * sizeof(short), 256);
    short* Bt2 = (short*)(ws + off);     off = align_up(off + (size_t)128 * HID_F * sizeof(short), 256);
    int* rowptr = (int*)(ws + off);      off = align_up(off + (size_t)(N_NODES + 1) * sizeof(int), 256);
    int* cntcur = (int*)(ws + off);      off = align_up(off + (size_t)N_NODES * sizeof(int), 256);
    int* partial = (int*)(ws + off);     off = align_up(off + (size_t)PRE_NB * sizeof(int), 256);
    int* bar = (int*)(ws + off);         off = align_up(off + 8 * sizeof(int), 256);
    int* adj = (int*)(ws + off);         off = align_up(off + (size_t)N_EDGES * sizeof(int), 256);
    unsigned short* hs1 = (unsigned short*)(ws + off); off = align_up(off + NB16, 256);
    unsigned short* hs2 = (unsigned short*)(ws + off); off = align_up(off + NB16, 256);
    (void)ws_size; (void)n_in; (void)in_sizes; (void)out_size;

    // grid-barrier counters must start at zero (workspace is poisoned)
    hipMemsetAsync(bar, 0, 8 * sizeof(int), stream);

    // fused preamble: degrees -> scan -> CSR bucket, bounds, transposes,
    // rootlin, dinv, out-zero. One launch, 5 fence-free grid barriers.
    pre_fused_kernel<<<PRE_NB, 256, 0, stream>>>(
        src, dst, batch, root, x, W1, W2,
        cntcur, rowptr, adj, partial, dinv, startv, cntg,
        Bt1, Bt2, rootlin, out, bar);

    // conv1 linear: hs1 = bf16( dinv .* (x @ W1) )
    mfma_gemm_kernel<IN_F, false, false><<<N_NODES / 64, 256, 0, stream>>>(
        x, Bt1, hs1, dinv, nullptr, nullptr, nullptr, nullptr, nullptr);

    // conv2 linear, pulling conv1 aggregation via CSR in the A-staging
    mfma_gemm_kernel<HID_F, true, true><<<N_NODES / 64, 256, 0, stream>>>(
        hs1, Bt2, hs2, dinv, b1, rootlin, batch, rowptr, adj);

    // fused conv2-aggregation + relu + graph mean + root gather
    dim3 mg(N_GRAPHS, 32);
    mean_kernel<<<mg, 128, 0, stream>>>(hs2, hs1, dinv, b1, b2, root, cntg, startv,
                                        rowptr, adj, out, 32);
}

// Round 3
// 459.788 us; speedup vs baseline: 2.8554x; 1.2043x over previous
//
#include <hip/hip_runtime.h>
#include <stddef.h>

// Problem constants (match reference setup_inputs)
constexpr int N_NODES = 200000;
constexpr int N_EDGES = 200000;
constexpr int N_GRAPHS = 128;
constexpr int IN_F = 256;
constexpr int HID_F = 128;
constexpr int OUT_F = 128;
constexpr int OUT_W = OUT_F + HID_F; // 256 output cols per graph
constexpr int SCAN_NB = (N_NODES + 1023) / 1024; // 196 blocks

typedef __attribute__((ext_vector_type(8))) short short8;   // bf16x8 MFMA A/B frag
typedef __attribute__((ext_vector_type(4))) float float4v;  // fp32x4 MFMA C/D frag

__device__ __forceinline__ short f2bf(float f) {
    union { float f; unsigned u; } v; v.f = f;
    unsigned r = v.u + 0x7fffu + ((v.u >> 16) & 1u);  // RNE
    return (short)(r >> 16);
}
__device__ __forceinline__ float bf2f(unsigned short s) {
    union { unsigned u; float f; } v; v.u = ((unsigned)s) << 16;
    return v.f;
}

// ---------------- small utility kernels (r2 post-mortem: multi-launch preamble
// is ~60us, cheaper than any grid-barrier fusion — launches were never the cost) ----

__global__ void edge_prep_kernel(const int* __restrict__ dst, int* __restrict__ cntin, int E) {
    int e = blockIdx.x * blockDim.x + threadIdx.x;
    if (e < E) atomicAdd(&cntin[dst[e]], 1);
}

__global__ __launch_bounds__(1024) void scan_reduce_kernel(const int* __restrict__ cnt,
                                                           int* __restrict__ partial, int n) {
    __shared__ int sm[1024];
    int t = threadIdx.x;
    int i = blockIdx.x * 1024 + t;
    sm[t] = (i < n) ? cnt[i] : 0;
    __syncthreads();
    for (int ofs = 512; ofs > 0; ofs >>= 1) {
        if (t < ofs) sm[t] += sm[t + ofs];
        __syncthreads();
    }
    if (t == 0) partial[blockIdx.x] = sm[0];
}

__global__ void scan_base_kernel(int* __restrict__ partial, int nb) {
    __shared__ int sm[256];
    int t = threadIdx.x;
    sm[t] = (t < nb) ? partial[t] : 0;
    __syncthreads();
    for (int ofs = 1; ofs < 256; ofs <<= 1) {
        int v = (t >= ofs) ? sm[t - ofs] : 0;
        __syncthreads();
        sm[t] += v;
        __syncthreads();
    }
    if (t < nb) partial[t] = (t == 0) ? 0 : sm[t - 1];
}

// local scan + base -> rp[i], cur[i]; fused dinv[i] = rsqrt(1+indeg).
// cnt aliases cur: each thread reads cnt[i] before writing cur[i] (same index).
__global__ __launch_bounds__(1024) void scan_final_kernel(const int* __restrict__ cnt,
                                                          const int* __restrict__ partial,
                                                          int* __restrict__ rp,
                                                          int* __restrict__ cur,
                                                          float* __restrict__ dinv, int n) {
    __shared__ int sm[1024];
    int t = threadIdx.x;
    int i = blockIdx.x * 1024 + t;
    int v = (i < n) ? cnt[i] : 0;
    sm[t] = v;
    __syncthreads();
    for (int ofs = 1; ofs < 1024; ofs <<= 1) {
        int u = (t >= ofs) ? sm[t - ofs] : 0;
        __syncthreads();
        sm[t] += u;
        __syncthreads();
    }
    int base = partial[blockIdx.x];
    if (i < n) {
        int ex = base + sm[t] - v; // exclusive
        rp[i] = ex;
        cur[i] = ex;
        dinv[i] = rsqrtf(1.0f + (float)v);
        if (i == n - 1) rp[n] = ex + v;
    }
}

__global__ void bucket_kernel(const int* __restrict__ src, const int* __restrict__ dst,
                              int* __restrict__ cur, int* __restrict__ adj, int E) {
    int e = blockIdx.x * blockDim.x + threadIdx.x;
    if (e < E) {
        int pos = atomicAdd(&cur[dst[e]], 1);
        adj[pos] = src[e];
    }
}

__global__ void bounds_kernel(const int* __restrict__ batch, int* __restrict__ start,
                              int* __restrict__ cnt, int n, int G) {
    __shared__ int s_start[N_GRAPHS + 1];
    int g = threadIdx.x;
    if (g < G) {
        int lo = 0, hi = n;
        while (lo < hi) {
            int mid = (lo + hi) >> 1;
            if (batch[mid] < g) lo = mid + 1; else hi = mid;
        }
        s_start[g] = lo;
        if (g == 0) s_start[G] = n;
    }
    __syncthreads();
    if (g < G) {
        start[g] = s_start[g];
        cnt[g] = s_start[g + 1] - s_start[g];
    }
}

__global__ void transpose_w_kernel(const float* __restrict__ W1, const float* __restrict__ W2,
                                   short* __restrict__ Bt1, short* __restrict__ Bt2) {
    int k = blockIdx.x;
    int n = threadIdx.x;
    if (k < IN_F) {
        Bt1[(size_t)n * IN_F + k] = f2bf(W1[(size_t)k * 128 + n]);
    } else {
        int kk = k - IN_F;
        Bt2[(size_t)n * HID_F + kk] = f2bf(W2[(size_t)kk * 128 + n]);
    }
}

// rootlin[g,f] += sum_{k in quarter} relu(x[root[g],k]) * W2[(HID_F+k)*OUT_F + f]
// 4-way k-split (grid.y) shortens the serial load chain; rootlin pre-zeroed.
__global__ void rootlin_kernel(const float* __restrict__ x, const int* __restrict__ root_index,
                               const float* __restrict__ W2, float* __restrict__ rootlin)
{
    int g = blockIdx.x;
    int s = blockIdx.y; // 0..3
    int f = threadIdx.x; // OUT_F threads
    int r = root_index[g];
    const float* xr = x + (size_t)r * IN_F;
    float acc = 0.f;
    int k0 = s * (IN_F / 4);
    for (int k = k0; k < k0 + IN_F / 4; ++k) {
        float xv = fmaxf(xr[k], 0.f);
        acc += xv * W2[(size_t)(HID_F + k) * OUT_F + f];
    }
    atomicAdd(&rootlin[(size_t)g * OUT_F + f], acc);
}

// ---------------- conv2 aggregation, standalone (r2 post-mortem) ----------------
// hsag[d,k] = bf16( relu( dinv[d]*(hs1[d,k] + sum_in hs1[adj,k]) + b1[k] ) )
// Was fused into conv2 GEMM A-staging, where the serial per-edge gather chain at
// 3 blocks/CU occupancy left the GEMM latency-bound. Standalone: no LDS, 8
// threads/row, 1.6M threads -> full TLP hides the random-row gather latency.
__global__ __launch_bounds__(256) void agg2_kernel(
    const unsigned short* __restrict__ hs1, const float* __restrict__ dinv,
    const float* __restrict__ b1v, const int* __restrict__ rp,
    const int* __restrict__ adj, unsigned short* __restrict__ hsag)
{
    int gid = blockIdx.x * 256 + threadIdx.x; // N_NODES*8 threads exactly
    int r = gid >> 3;
    int c0 = (gid & 7) * 16; // 16 shorts = 32B per thread
    const unsigned short* hp = hs1 + (size_t)r * 128 + c0;
    float sum[16];
    {
        short8 h0 = *(const short8*)hp;
        short8 h1 = *(const short8*)(hp + 8);
        #pragma unroll
        for (int q = 0; q < 8; ++q) {
            sum[q] = bf2f((unsigned short)h0[q]);
            sum[8 + q] = bf2f((unsigned short)h1[q]);
        }
    }
    int e0 = rp[r], e1 = rp[r + 1];
    for (int e = e0; e < e1; ++e) {
        const unsigned short* qp = hs1 + (size_t)adj[e] * 128 + c0;
        short8 h0 = *(const short8*)qp;
        short8 h1 = *(const short8*)(qp + 8);
        #pragma unroll
        for (int q = 0; q < 8; ++q) {
            sum[q] += bf2f((unsigned short)h0[q]);
            sum[8 + q] += bf2f((unsigned short)h1[q]);
        }
    }
    float di = dinv[r];
    short8 s0, s1;
    #pragma unroll
    for (int q = 0; q < 8; ++q) {
        s0[q] = f2bf(fmaxf(di * sum[q] + b1v[c0 + q], 0.f));
        s1[q] = f2bf(fmaxf(di * sum[8 + q] + b1v[c0 + 8 + q], 0.f));
    }
    unsigned short* op = hsag + (size_t)r * 128 + c0;
    *(short8*)op = s0;
    *(short8*)(op + 8) = s1;
}

// ---------------- bf16 MFMA GEMM ----------------
// out[M,128] = op(A)[M,KTOT] @ B[KTOT,128], epilogue v = dinv[row]*(acc [+ rootlin]),
// stored bf16. ABF16: A already bf16 row-major [M][KTOT] -> direct short8 staging.
template<int KTOT, bool ABF16, bool ADDROOT>
__global__ __launch_bounds__(256) void mfma_gemm_kernel(
    const void* __restrict__ Ap, const short* __restrict__ Bt,
    unsigned short* __restrict__ outp,
    const float* __restrict__ dinv,
    const float* __restrict__ rootlin, const int* __restrict__ batch)
{
    // stride 136 shorts = 272B: bank stride 68 == 4 mod 32 -> 2-way conflicts only (free, m136)
    __shared__ __align__(16) short As[64][136];
    __shared__ __align__(16) short Bs[128][136];

    const int tid = threadIdx.x;
    const int wave = tid >> 6;
    const int lane = tid & 63;
    const int quad = lane >> 4;
    const int l16  = lane & 15;
    const int row0 = blockIdx.x * 64;

    float4v acc[8];
    #pragma unroll
    for (int c = 0; c < 8; ++c) acc[c] = (float4v){0.f, 0.f, 0.f, 0.f};

    const int arow = tid >> 2;
    const int ac8 = (tid & 3) * 8;
    const int bn = tid >> 1;
    const int bk = (tid & 1) * 64;

    for (int kb = 0; kb < KTOT / 128; ++kb) {
        {
            const short* bp = Bt + (size_t)bn * KTOT + kb * 128 + bk;
            #pragma unroll
            for (int j = 0; j < 8; ++j)
                *(short8*)&Bs[bn][bk + 8 * j] = *(const short8*)(bp + 8 * j);
        }
        if (ABF16) {
            const unsigned short* A = (const unsigned short*)Ap;
            const unsigned short* ap = A + (size_t)(row0 + arow) * KTOT + kb * 128 + ac8;
            #pragma unroll
            for (int jj = 0; jj < 4; ++jj)
                *(short8*)&As[arow][ac8 + 32 * jj] = *(const short8*)(ap + 32 * jj);
        } else {
            const float* A = (const float*)Ap;
            const float* ap = A + (size_t)(row0 + arow) * KTOT + kb * 128 + ac8;
            #pragma unroll
            for (int jj = 0; jj < 4; ++jj) {
                float4 f0 = *(const float4*)(ap + 32 * jj);
                float4 f1 = *(const float4*)(ap + 32 * jj + 4);
                short8 s;
                s[0] = f2bf(f0.x); s[1] = f2bf(f0.y); s[2] = f2bf(f0.z); s[3] = f2bf(f0.w);
                s[4] = f2bf(f1.x); s[5] = f2bf(f1.y); s[6] = f2bf(f1.z); s[7] = f2bf(f1.w);
                *(short8*)&As[arow][ac8 + 32 * jj] = s;
            }
        }
        __syncthreads();
        #pragma unroll
        for (int ks = 0; ks < 4; ++ks) {
            short8 af = *(const short8*)&As[wave * 16 + l16][ks * 32 + quad * 8];
            #pragma unroll
            for (int c = 0; c < 8; ++c) {
                short8 bf = *(const short8*)&Bs[c * 16 + l16][ks * 32 + quad * 8];
                acc[c] = __builtin_amdgcn_mfma_f32_16x16x32_bf16(af, bf, acc[c], 0, 0, 0);
            }
        }
        __syncthreads();
    }

    #pragma unroll
    for (int r = 0; r < 4; ++r) {
        int row = row0 + wave * 16 + quad * 4 + r;
        float di = dinv[row];
        const float* rl = nullptr;
        if (ADDROOT) rl = rootlin + (size_t)batch[row] * 128;
        #pragma unroll
        for (int c = 0; c < 8; ++c) {
            int col = c * 16 + l16;
            float v = acc[c][r];
            if (ADDROOT) v += rl[col];
            outp[(size_t)row * 128 + col] = (unsigned short)f2bf(v * di);
        }
    }
}

// out[g,0:128]   = (1/n) sum_seg relu(dinv[i]*(hs2[i]+sum_in hs2[adj]) + b2)   (pull-mode conv2 agg)
// out[g,128:256] = n>0 ? dinv[r]*(hs1[r]+sum_in hs1[adj]) + b1 : 0             (x2[root] on the fly)
// chunks=128 (r2): per-thread serial chain ~12 nodes instead of ~49.
__global__ void mean_kernel(const unsigned short* __restrict__ hs2,
                            const unsigned short* __restrict__ hs1,
                            const float* __restrict__ dinv, const float* __restrict__ b1v,
                            const float* __restrict__ b2v, const int* __restrict__ root_index,
                            const int* __restrict__ cnt, const int* __restrict__ start,
                            const int* __restrict__ rp, const int* __restrict__ adj,
                            float* __restrict__ out, int chunks)
{
    int g = blockIdx.x;
    int c = blockIdx.y;
    int f = threadIdx.x; // 128
    int s = start[g], n = cnt[g];
    int per = (n + chunks - 1) / chunks;
    int lo = s + c * per;
    int hi = min(s + n, lo + per);
    float bb = b2v[f];
    float accv = 0.f;
    for (int i = lo; i < hi; ++i) {
        float v = bf2f(hs2[(size_t)i * 128 + f]);
        int e0 = rp[i], e1 = rp[i + 1];
        for (int e = e0; e < e1; ++e)
            v += bf2f(hs2[(size_t)adj[e] * 128 + f]);
        accv += fmaxf(dinv[i] * v + bb, 0.f);
    }
    if (hi > lo)
        atomicAdd(&out[(size_t)g * OUT_W + f], accv / (float)max(n, 1));
    if (c == 0) {
        int r = root_index[g];
        float v = 0.f;
        if (n > 0) {
            v = bf2f(hs1[(size_t)r * 128 + f]);
            int e0 = rp[r], e1 = rp[r + 1];
            for (int e = e0; e < e1; ++e)
                v += bf2f(hs1[(size_t)adj[e] * 128 + f]);
            v = dinv[r] * v + b1v[f];
        }
        out[(size_t)g * OUT_W + HID_F + f] = v;
    }
}

// ---------------- launch ----------------

static inline size_t align_up(size_t x, size_t a) { return (x + a - 1) / a * a; }

extern "C" void kernel_launch(void* const* d_in, const int* in_sizes, int n_in,
                              void* d_out, int out_size, void* d_ws, size_t ws_size,
                              hipStream_t stream) {
    const float* x = (const float*)d_in[0];
    const int* ei = (const int*)d_in[1];
    const int* batch = (const int*)d_in[2];
    const int* root = (const int*)d_in[3];
    const float* W1 = (const float*)d_in[4];
    const float* b1 = (const float*)d_in[5];
    const float* W2 = (const float*)d_in[6];
    const float* b2 = (const float*)d_in[7];
    float* out = (float*)d_out;

    const int* src = ei;
    const int* dst = ei + N_EDGES;

    // workspace carve-up
    char* ws = (char*)d_ws;
    size_t off = 0;
    const size_t NB16 = (size_t)N_NODES * 128 * sizeof(unsigned short); // 51.2 MB

    float* dinv = (float*)(ws + off);    off = align_up(off + (size_t)N_NODES * sizeof(float), 256);
    int* cntg = (int*)(ws + off);        off = align_up(off + N_GRAPHS * sizeof(int), 256);
    int* startv = (int*)(ws + off);      off = align_up(off + N_GRAPHS * sizeof(int), 256);
    float* rootlin = (float*)(ws + off); off = align_up(off + (size_t)N_GRAPHS * OUT_F * sizeof(float), 256);
    short* Bt1 = (short*)(ws + off);     off = align_up(off + (size_t)128 * IN_F * sizeof(short), 256);
    short* Bt2 = (short*)(ws + off);     off = align_up(off + (size_t)128 * HID_F * sizeof(short), 256);
    int* rowptr = (int*)(ws + off);      off = align_up(off + (size_t)(N_NODES + 1) * sizeof(int), 256);
    int* cursor = (int*)(ws + off);      off = align_up(off + (size_t)N_NODES * sizeof(int), 256);
    int* partial = (int*)(ws + off);     off = align_up(off + (size_t)SCAN_NB * sizeof(int), 256);
    int* adj = (int*)(ws + off);         off = align_up(off + (size_t)N_EDGES * sizeof(int), 256);
    unsigned short* hs1 = (unsigned short*)(ws + off);  off = align_up(off + NB16, 256);
    unsigned short* hs2 = (unsigned short*)(ws + off);  off = align_up(off + NB16, 256);
    unsigned short* hsag = (unsigned short*)(ws + off); off = align_up(off + NB16, 256);
    (void)ws_size; (void)n_in; (void)in_sizes; (void)out_size;

    // in-degree -> CSR-by-dst via hierarchical scan (+ fused dinv) + bucket
    hipMemsetAsync(cursor, 0, (size_t)N_NODES * sizeof(int), stream);
    edge_prep_kernel<<<(N_EDGES + 255) / 256, 256, 0, stream>>>(dst, cursor, N_EDGES);
    scan_reduce_kernel<<<SCAN_NB, 1024, 0, stream>>>(cursor, partial, N_NODES);
    scan_base_kernel<<<1, 256, 0, stream>>>(partial, SCAN_NB);
    scan_final_kernel<<<SCAN_NB, 1024, 0, stream>>>(cursor, partial, rowptr, cursor, dinv, N_NODES);
    bucket_kernel<<<(N_EDGES + 255) / 256, 256, 0, stream>>>(src, dst, cursor, adj, N_EDGES);
    bounds_kernel<<<1, N_GRAPHS, 0, stream>>>(batch, startv, cntg, N_NODES, N_GRAPHS);

    // weight pre-transposes + rootlin (4-way k-split, atomic accumulate)
    transpose_w_kernel<<<IN_F + HID_F, 128, 0, stream>>>(W1, W2, Bt1, Bt2);
    hipMemsetAsync(rootlin, 0, (size_t)N_GRAPHS * OUT_F * sizeof(float), stream);
    dim3 rg(N_GRAPHS, 4);
    rootlin_kernel<<<rg, OUT_F, 0, stream>>>(x, root, W2, rootlin);

    // conv1 linear: hs1 = bf16( dinv .* (x @ W1) )
    mfma_gemm_kernel<IN_F, false, false><<<N_NODES / 64, 256, 0, stream>>>(
        x, Bt1, hs1, dinv, nullptr, nullptr);

    // conv2 aggregation (standalone, TLP-rich): hsag = relu(dinv.*(hs1+gather)+b1)
    agg2_kernel<<<(N_NODES * 8) / 256, 256, 0, stream>>>(hs1, dinv, b1, rowptr, adj, hsag);

    // conv2 linear (pure streaming bf16 GEMM):
    // hs2 = bf16( dinv .* ( hsag @ W2[0:128] + rootlin[batch] ) )
    mfma_gemm_kernel<HID_F, true, true><<<N_NODES / 64, 256, 0, stream>>>(
        hsag, Bt2, hs2, dinv, rootlin, batch);

    // fused conv2-aggregation + relu + graph mean + root gather
    hipMemsetAsync(out, 0, (size_t)N_GRAPHS * OUT_W * sizeof(float), stream);
    constexpr int CHUNKS = 128;
    dim3 mg(N_GRAPHS, CHUNKS);
    mean_kernel<<<mg, 128, 0, stream>>>(hs2, hs1, dinv, b1, b2, root, cntg, startv,
                                        rowptr, adj, out, CHUNKS);
}